// Round 7
// baseline (402.155 us; speedup 1.0000x reference)
//
#include <hip/hip_runtime.h>

#define NNODES 50000
#define NEDGES 500000
#define DIN 128
#define DHID 256
#define MPAD 50048   // 1564 blocks * 32 rows
#define NI4 12500
#define NSB 49

typedef unsigned short u16;
typedef __attribute__((ext_vector_type(8))) short short8;
typedef __attribute__((ext_vector_type(4))) float f32x4;

__device__ __forceinline__ float bf2f(unsigned int u) {
  union { unsigned int i; float f; } v; v.i = u << 16; return v.f;
}
__device__ __forceinline__ u16 f2bf(float f) {
  union { unsigned int i; float f; } v; v.f = f;
  unsigned int x = v.i;
  x += 0x7fffu + ((x >> 16) & 1u);   // RNE
  return (u16)(x >> 16);
}
__device__ __forceinline__ void split_bf(float x, u16& hi, u16& lo) {
  hi = f2bf(x);
  lo = f2bf(x - bf2f(hi));
}
__device__ __forceinline__ u16 f2h(float f) {
  union { _Float16 h; u16 u; } v; v.h = (_Float16)f; return v.u;
}
__device__ __forceinline__ float h2f(unsigned int u) {
  union { _Float16 h; u16 u; } v; v.u = (u16)u; return (float)v.h;
}

__global__ void k_zero_i32(int* __restrict__ p, int n) {
  int i = blockIdx.x * blockDim.x + threadIdx.x;
  if (i < n) p[i] = 0;
}

__global__ void k_hist(const int* __restrict__ dst, int* __restrict__ deg, int e) {
  int i = blockIdx.x * blockDim.x + threadIdx.x;
  if (i < e) atomicAdd(&deg[dst[i]], 1);
}

__global__ __launch_bounds__(256) void k_blocksum(const int* __restrict__ deg,
                                                  int* __restrict__ partials) {
  __shared__ int red[256];
  int tid = threadIdx.x;
  int t4 = blockIdx.x * 256 + tid;
  int sum = 0;
  if (t4 < NI4) {
    int4 v = ((const int4*)deg)[t4];
    sum = v.x + v.y + v.z + v.w;
  }
  red[tid] = sum;
  __syncthreads();
  for (int off = 128; off > 0; off >>= 1) {
    if (tid < off) red[tid] += red[tid + off];
    __syncthreads();
  }
  if (tid == 0) partials[blockIdx.x] = red[0];
}

// exclusive scan -> row_ptr; fused: dinv = rsqrt(deg+1), zero deg (cursor reuse)
__global__ __launch_bounds__(256) void k_scan2(int* __restrict__ deg,
                                               const int* __restrict__ partials,
                                               int* __restrict__ row_ptr,
                                               float* __restrict__ dinv) {
  __shared__ int sdata[256];
  __shared__ int sprefix;
  int tid = threadIdx.x, bid = blockIdx.x;
  int t4 = bid * 256 + tid;
  int4 v = make_int4(0, 0, 0, 0);
  if (t4 < NI4) v = ((const int4*)deg)[t4];
  int tsum = v.x + v.y + v.z + v.w;
  sdata[tid] = tsum;
  if (tid == 0) {
    int pre = 0;
    for (int b = 0; b < bid; ++b) pre += partials[b];
    sprefix = pre;
  }
  __syncthreads();
  for (int off = 1; off < 256; off <<= 1) {
    int val = (tid >= off) ? sdata[tid - off] : 0;
    __syncthreads();
    sdata[tid] += val;
    __syncthreads();
  }
  if (t4 < NI4) {
    int run = sdata[tid] - tsum + sprefix;
    int base = t4 * 4;
    float4 dv;
    dv.x = rsqrtf((float)v.x + 1.0f);
    dv.y = rsqrtf((float)v.y + 1.0f);
    dv.z = rsqrtf((float)v.z + 1.0f);
    dv.w = rsqrtf((float)v.w + 1.0f);
    *(float4*)(dinv + base) = dv;
    row_ptr[base + 0] = run; run += v.x;
    row_ptr[base + 1] = run; run += v.y;
    row_ptr[base + 2] = run; run += v.z;
    row_ptr[base + 3] = run; run += v.w;
    if (base + 4 == NNODES) row_ptr[NNODES] = run;
    ((int4*)deg)[t4] = make_int4(0, 0, 0, 0);
  }
}

__global__ void k_fill(const int* __restrict__ src, const int* __restrict__ dst,
                       const float* __restrict__ dinv, const int* __restrict__ row_ptr,
                       int* __restrict__ cursor, int* __restrict__ csr_src,
                       float* __restrict__ csr_nrm, int e) {
  int i = blockIdx.x * blockDim.x + threadIdx.x;
  if (i < e) {
    int d = dst[i], s = src[i];
    int pos = row_ptr[d] + atomicAdd(&cursor[d], 1);
    csr_src[pos] = s;
    csr_nrm[pos] = dinv[s] * dinv[d];
  }
}

// x f32 -> f16
__global__ void k_x2f16(const float* __restrict__ x, u16* __restrict__ xh, int total4) {
  int i = blockIdx.x * blockDim.x + threadIdx.x;
  if (i >= total4) return;
  float4 v = ((const float4*)x)[i];
  ushort4 o;
  o.x = f2h(v.x); o.y = f2h(v.y); o.z = f2h(v.z); o.w = f2h(v.w);
  ((ushort4*)xh)[i] = o;
}

// fused W1/W2/W3 split+swizzle into B-fragment order
__global__ void k_splitW3(const float* __restrict__ W1f, u16* __restrict__ W1h, u16* __restrict__ W1l,
                          const float* __restrict__ W2f, u16* __restrict__ W2h, u16* __restrict__ W2l,
                          const float* __restrict__ W3f, u16* __restrict__ W3h, u16* __restrict__ W3l) {
  int i = blockIdx.x * blockDim.x + threadIdx.x;
  const int s1 = DIN * 256, s2 = s1 + DHID * 256, s3 = s2 + DHID * 256;
  if (i >= s3) return;
  const float* W; u16 *hi, *lo; int li;
  if (i < s1)      { W = W1f; hi = W1h; lo = W1l; li = i; }
  else if (i < s2) { W = W2f; hi = W2h; lo = W2l; li = i - s1; }
  else             { W = W3f; hi = W3h; lo = W3l; li = i - s2; }
  int k = li >> 8, n = li & 255;
  int t = k >> 5, q = (k >> 3) & 3, j = k & 7;
  int c = n >> 4, m = n & 15;
  size_t pos = (((size_t)(t * 16 + c)) * 64 + q * 16 + m) * 8 + j;
  u16 h, l;
  split_bf(W[li], h, l);
  hi[pos] = h;
  lo[pos] = l;
}

// Aggregate-first gather: A[node] = dinv[node]^2 * h[node] + sum_e w_e * h[src_e]
// h is f16, width = 64*CPL. Output: split-bf16 (ahi/alo), row-major width cols.
template<int CPL>
__global__ __launch_bounds__(256) void k_aggF(const u16* __restrict__ hf,
                                              const float* __restrict__ dinv,
                                              const int* __restrict__ row_ptr,
                                              const int* __restrict__ csr_src,
                                              const float* __restrict__ csr_nrm,
                                              u16* __restrict__ ahi,
                                              u16* __restrict__ alo, int n) {
  const int W = 64 * CPL;
  int node = blockIdx.x * 4 + (threadIdx.x >> 6);
  if (node >= n) return;
  int lane = threadIdx.x & 63;
  int c = lane * CPL;

  float acc[CPL];
  float di = dinv[node];
  float s2 = di * di;

  auto ldh = [&](int row, float* v) {
    const u16* p = hf + (size_t)row * W + c;
    if constexpr (CPL == 2) {
      unsigned int u = *(const unsigned int*)p;
      v[0] = h2f(u & 0xffffu); v[1] = h2f(u >> 16);
    } else {
      uint2 u = *(const uint2*)p;
      v[0] = h2f(u.x & 0xffffu); v[1] = h2f(u.x >> 16);
      v[2] = h2f(u.y & 0xffffu); v[3] = h2f(u.y >> 16);
    }
  };

  {
    float v[CPL];
    ldh(node, v);
#pragma unroll
    for (int j = 0; j < CPL; ++j) acc[j] = s2 * v[j];
  }

  int p = row_ptr[node], p1 = row_ptr[node + 1];
  for (; p + 4 <= p1; p += 4) {
    int s0 = csr_src[p], s1 = csr_src[p + 1], s2i = csr_src[p + 2], s3 = csr_src[p + 3];
    float w0 = csr_nrm[p], w1 = csr_nrm[p + 1], w2 = csr_nrm[p + 2], w3 = csr_nrm[p + 3];
    float v0[CPL], v1[CPL], v2[CPL], v3[CPL];
    ldh(s0, v0); ldh(s1, v1); ldh(s2i, v2); ldh(s3, v3);
#pragma unroll
    for (int j = 0; j < CPL; ++j) {
      acc[j] = fmaf(w0, v0[j], acc[j]);
      acc[j] = fmaf(w1, v1[j], acc[j]);
      acc[j] = fmaf(w2, v2[j], acc[j]);
      acc[j] = fmaf(w3, v3[j], acc[j]);
    }
  }
  for (; p < p1; ++p) {
    int s = csr_src[p];
    float w = csr_nrm[p];
    float v[CPL];
    ldh(s, v);
#pragma unroll
    for (int j = 0; j < CPL; ++j) acc[j] = fmaf(w, v[j], acc[j]);
  }

  u16 hq[CPL], lq[CPL];
#pragma unroll
  for (int j = 0; j < CPL; ++j) split_bf(acc[j], hq[j], lq[j]);
  if constexpr (CPL == 2) {
    ushort2 h2v, l2v;
    h2v.x = hq[0]; h2v.y = hq[1];
    l2v.x = lq[0]; l2v.y = lq[1];
    *(ushort2*)(ahi + (size_t)node * W + c) = h2v;
    *(ushort2*)(alo + (size_t)node * W + c) = l2v;
  } else {
    ushort4 h4v, l4v;
    h4v.x = hq[0]; h4v.y = hq[1]; h4v.z = hq[2]; h4v.w = hq[3];
    l4v.x = lq[0]; l4v.y = lq[1]; l4v.z = lq[2]; l4v.w = lq[3];
    *(ushort4*)(ahi + (size_t)node * W + c) = h4v;
    *(ushort4*)(alo + (size_t)node * W + c) = l4v;
  }
}

// C = (Ahi+Alo) @ (Bhi+Blo) + bias, 3-pass split-bf16 MFMA.
// block = 32 rows x 256 cols; 4 waves, each 32 rows x 64 cols (4 c-tiles).
// Grid = MPAD/32 = 1564 blocks for occupancy. No LDS.
// EPI 0: relu + f16 store to hf16 (all rows). EPI 1: f32 store to outf, rows<NNODES.
template<int K, int EPI>
__global__ __launch_bounds__(256, 4) void k_gemm_mfma(const u16* __restrict__ Ahi,
                                                      const u16* __restrict__ Alo,
                                                      const u16* __restrict__ Bhi,
                                                      const u16* __restrict__ Blo,
                                                      const float* __restrict__ bias,
                                                      u16* __restrict__ hf16,
                                                      float* __restrict__ outf) {
  const int lane = threadIdx.x & 63;
  const int wave = threadIdx.x >> 6;
  const int m0 = blockIdx.x * 32;
  const int ct0 = wave * 4;   // first c-tile of this wave

  f32x4 acc0[4], acc1[4];
#pragma unroll
  for (int c = 0; c < 4; ++c) {
    acc0[c] = {0.f, 0.f, 0.f, 0.f};
    acc1[c] = {0.f, 0.f, 0.f, 0.f};
  }

  const u16* a0h = Ahi + (size_t)(m0 + (lane & 15)) * K + ((lane >> 4) * 8);
  const u16* a0l = Alo + (size_t)(m0 + (lane & 15)) * K + ((lane >> 4) * 8);
  const u16* a1h = a0h + (size_t)16 * K;
  const u16* a1l = a0l + (size_t)16 * K;

  for (int t = 0; t < K / 32; ++t) {
    short8 ah0 = *(const short8*)(a0h + t * 32);
    short8 al0 = *(const short8*)(a0l + t * 32);
    short8 ah1 = *(const short8*)(a1h + t * 32);
    short8 al1 = *(const short8*)(a1l + t * 32);
    const u16* bb = Bhi + ((size_t)(t * 16 + ct0) * 64 + lane) * 8;
    const u16* bbl = Blo + ((size_t)(t * 16 + ct0) * 64 + lane) * 8;
#pragma unroll
    for (int c = 0; c < 4; ++c) {
      short8 bh = *(const short8*)(bb + (size_t)c * 512);
      short8 bl = *(const short8*)(bbl + (size_t)c * 512);
      acc0[c] = __builtin_amdgcn_mfma_f32_16x16x32_bf16(ah0, bh, acc0[c], 0, 0, 0);
      acc0[c] = __builtin_amdgcn_mfma_f32_16x16x32_bf16(al0, bh, acc0[c], 0, 0, 0);
      acc0[c] = __builtin_amdgcn_mfma_f32_16x16x32_bf16(ah0, bl, acc0[c], 0, 0, 0);
      acc1[c] = __builtin_amdgcn_mfma_f32_16x16x32_bf16(ah1, bh, acc1[c], 0, 0, 0);
      acc1[c] = __builtin_amdgcn_mfma_f32_16x16x32_bf16(al1, bh, acc1[c], 0, 0, 0);
      acc1[c] = __builtin_amdgcn_mfma_f32_16x16x32_bf16(ah1, bl, acc1[c], 0, 0, 0);
    }
  }

  const int cbase = lane & 15;
  const int r0 = m0 + ((lane >> 4) * 4);
#pragma unroll
  for (int c = 0; c < 4; ++c) {
    int col = (ct0 + c) * 16 + cbase;
    float bv = bias[col];
#pragma unroll
    for (int r = 0; r < 4; ++r) {
      float v0 = acc0[c][r] + bv;
      float v1 = acc1[c][r] + bv;
      if (EPI == 0) {
        v0 = fmaxf(v0, 0.f);
        v1 = fmaxf(v1, 0.f);
        hf16[(size_t)(r0 + r) * 256 + col] = f2h(v0);
        hf16[(size_t)(r0 + 16 + r) * 256 + col] = f2h(v1);
      } else {
        if (r0 + r < NNODES) outf[(size_t)(r0 + r) * 256 + col] = v0;
        if (r0 + 16 + r < NNODES) outf[(size_t)(r0 + 16 + r) * 256 + col] = v1;
      }
    }
  }
}

extern "C" void kernel_launch(void* const* d_in, const int* in_sizes, int n_in,
                              void* d_out, int out_size, void* d_ws, size_t ws_size,
                              hipStream_t stream) {
  const float* x  = (const float*)d_in[0];
  const int*   ei = (const int*)d_in[1];
  const float* W1 = (const float*)d_in[2];
  const float* b1 = (const float*)d_in[3];
  const float* W2 = (const float*)d_in[4];
  const float* b2 = (const float*)d_in[5];
  const float* W3 = (const float*)d_in[6];
  const float* b3 = (const float*)d_in[7];
  float* out = (float*)d_out;
  (void)in_sizes; (void)n_in; (void)out_size; (void)ws_size;

  char* ws = (char*)d_ws;
  size_t off = 0;
  auto alloc = [&](size_t bytes) -> void* {
    void* p = (void*)(ws + off);
    off += (bytes + 255) & ~(size_t)255;
    return p;
  };
  float* dinv    = (float*)alloc((size_t)NNODES * 4);
  int*   deg     = (int*)alloc((size_t)NNODES * 4);
  int*   row_ptr = (int*)alloc((size_t)(NNODES + 1) * 4);
  int*   partials= (int*)alloc((size_t)NSB * 4);
  int*   csr_src = (int*)alloc((size_t)NEDGES * 4);
  float* csr_nrm = (float*)alloc((size_t)NEDGES * 4);
  u16*   xh      = (u16*)alloc((size_t)NNODES * DIN * 2);    // x as f16
  u16*   hbuf    = (u16*)alloc((size_t)MPAD * 256 * 2);      // h as f16 (gather target)
  u16*   A1hi    = (u16*)alloc((size_t)MPAD * DIN * 2);      // agg(x) split
  u16*   A1lo    = (u16*)alloc((size_t)MPAD * DIN * 2);
  u16*   A2hi    = (u16*)alloc((size_t)MPAD * 256 * 2);      // agg(h) split
  u16*   A2lo    = (u16*)alloc((size_t)MPAD * 256 * 2);
  u16*   W1hi    = (u16*)alloc((size_t)DIN * 256 * 2);
  u16*   W1lo    = (u16*)alloc((size_t)DIN * 256 * 2);
  u16*   W2hi    = (u16*)alloc((size_t)DHID * 256 * 2);
  u16*   W2lo    = (u16*)alloc((size_t)DHID * 256 * 2);
  u16*   W3hi    = (u16*)alloc((size_t)DHID * 256 * 2);
  u16*   W3lo    = (u16*)alloc((size_t)DHID * 256 * 2);

  const int* e_src = ei;
  const int* e_dst = ei + NEDGES;

  const int tb = 256;
  k_zero_i32<<<(NNODES + tb - 1) / tb, tb, 0, stream>>>(deg, NNODES);
  k_hist<<<(NEDGES + tb - 1) / tb, tb, 0, stream>>>(e_dst, deg, NEDGES);
  k_blocksum<<<NSB, 256, 0, stream>>>(deg, partials);
  k_scan2<<<NSB, 256, 0, stream>>>(deg, partials, row_ptr, dinv);
  k_fill<<<(NEDGES + tb - 1) / tb, tb, 0, stream>>>(e_src, e_dst, dinv, row_ptr, deg,
                                                    csr_src, csr_nrm, NEDGES);

  int x4 = NNODES * DIN / 4;
  k_x2f16<<<(x4 + tb - 1) / tb, tb, 0, stream>>>(x, xh, x4);
  int wtot = (DIN + DHID + DHID) * 256;
  k_splitW3<<<(wtot + tb - 1) / tb, tb, 0, stream>>>(W1, W1hi, W1lo,
                                                     W2, W2hi, W2lo,
                                                     W3, W3hi, W3lo);

  const int gblocks = MPAD / 32;           // 1564
  const int ablocks = (NNODES + 3) / 4;

  // layer 1: agg(x) then GEMM(+b1+relu) -> h f16
  k_aggF<2><<<ablocks, 256, 0, stream>>>(xh, dinv, row_ptr, csr_src, csr_nrm,
                                         A1hi, A1lo, NNODES);
  k_gemm_mfma<DIN, 0><<<gblocks, 256, 0, stream>>>(A1hi, A1lo, W1hi, W1lo, b1,
                                                   hbuf, nullptr);
  // layer 2: agg(h1) then GEMM(+b2+relu) -> h f16
  k_aggF<4><<<ablocks, 256, 0, stream>>>(hbuf, dinv, row_ptr, csr_src, csr_nrm,
                                         A2hi, A2lo, NNODES);
  k_gemm_mfma<DHID, 0><<<gblocks, 256, 0, stream>>>(A2hi, A2lo, W2hi, W2lo, b2,
                                                    hbuf, nullptr);
  // layer 3: agg(h2) then GEMM(+b3) -> out f32
  k_aggF<4><<<ablocks, 256, 0, stream>>>(hbuf, dinv, row_ptr, csr_src, csr_nrm,
                                         A2hi, A2lo, NNODES);
  k_gemm_mfma<DHID, 1><<<gblocks, 256, 0, stream>>>(A2hi, A2lo, W3hi, W3lo, b3,
                                                    nullptr, out);
}

// Round 8
// 343.420 us; speedup vs baseline: 1.1710x; 1.1710x over previous
//
#include <hip/hip_runtime.h>

#define NNODES 50000
#define NEDGES 500000
#define DIN 128
#define DHID 256
#define MPAD 50048   // 782 blocks * 64 rows
#define NI4 12500
#define NSB 49

typedef unsigned short u16;
typedef __attribute__((ext_vector_type(8))) _Float16 half8;
typedef __attribute__((ext_vector_type(4))) float f32x4;

__device__ __forceinline__ u16 f2h(float f) {
  union { _Float16 h; u16 u; } v; v.h = (_Float16)f; return v.u;
}
__device__ __forceinline__ float h2f(unsigned int u) {
  union { _Float16 h; u16 u; } v; v.u = (u16)u; return (float)v.h;
}

#define GLDS16(g, l) __builtin_amdgcn_global_load_lds( \
    (const __attribute__((address_space(1))) void*)(g), \
    (__attribute__((address_space(3))) void*)(l), 16, 0, 0)

__global__ void k_zero_i32(int* __restrict__ p, int n) {
  int i = blockIdx.x * blockDim.x + threadIdx.x;
  if (i < n) p[i] = 0;
}

__global__ void k_hist(const int* __restrict__ dst, int* __restrict__ deg, int e) {
  int i = blockIdx.x * blockDim.x + threadIdx.x;
  if (i < e) atomicAdd(&deg[dst[i]], 1);
}

__global__ __launch_bounds__(256) void k_blocksum(const int* __restrict__ deg,
                                                  int* __restrict__ partials) {
  __shared__ int red[256];
  int tid = threadIdx.x;
  int t4 = blockIdx.x * 256 + tid;
  int sum = 0;
  if (t4 < NI4) {
    int4 v = ((const int4*)deg)[t4];
    sum = v.x + v.y + v.z + v.w;
  }
  red[tid] = sum;
  __syncthreads();
  for (int off = 128; off > 0; off >>= 1) {
    if (tid < off) red[tid] += red[tid + off];
    __syncthreads();
  }
  if (tid == 0) partials[blockIdx.x] = red[0];
}

// exclusive scan -> row_ptr; fused: dinv = rsqrt(deg+1), zero deg (cursor reuse)
__global__ __launch_bounds__(256) void k_scan2(int* __restrict__ deg,
                                               const int* __restrict__ partials,
                                               int* __restrict__ row_ptr,
                                               float* __restrict__ dinv) {
  __shared__ int sdata[256];
  __shared__ int sprefix;
  int tid = threadIdx.x, bid = blockIdx.x;
  int t4 = bid * 256 + tid;
  int4 v = make_int4(0, 0, 0, 0);
  if (t4 < NI4) v = ((const int4*)deg)[t4];
  int tsum = v.x + v.y + v.z + v.w;
  sdata[tid] = tsum;
  if (tid == 0) {
    int pre = 0;
    for (int b = 0; b < bid; ++b) pre += partials[b];
    sprefix = pre;
  }
  __syncthreads();
  for (int off = 1; off < 256; off <<= 1) {
    int val = (tid >= off) ? sdata[tid - off] : 0;
    __syncthreads();
    sdata[tid] += val;
    __syncthreads();
  }
  if (t4 < NI4) {
    int run = sdata[tid] - tsum + sprefix;
    int base = t4 * 4;
    float4 dv;
    dv.x = rsqrtf((float)v.x + 1.0f);
    dv.y = rsqrtf((float)v.y + 1.0f);
    dv.z = rsqrtf((float)v.z + 1.0f);
    dv.w = rsqrtf((float)v.w + 1.0f);
    *(float4*)(dinv + base) = dv;
    row_ptr[base + 0] = run; run += v.x;
    row_ptr[base + 1] = run; run += v.y;
    row_ptr[base + 2] = run; run += v.z;
    row_ptr[base + 3] = run; run += v.w;
    if (base + 4 == NNODES) row_ptr[NNODES] = run;
    ((int4*)deg)[t4] = make_int4(0, 0, 0, 0);
  }
}

__global__ void k_fill(const int* __restrict__ src, const int* __restrict__ dst,
                       const float* __restrict__ dinv, const int* __restrict__ row_ptr,
                       int* __restrict__ cursor, int* __restrict__ csr_src,
                       float* __restrict__ csr_nrm, int e) {
  int i = blockIdx.x * blockDim.x + threadIdx.x;
  if (i < e) {
    int d = dst[i], s = src[i];
    int pos = row_ptr[d] + atomicAdd(&cursor[d], 1);
    csr_src[pos] = s;
    csr_nrm[pos] = dinv[s] * dinv[d];
  }
}

// x f32 -> f16
__global__ void k_x2f16(const float* __restrict__ x, u16* __restrict__ xh, int total4) {
  int i = blockIdx.x * blockDim.x + threadIdx.x;
  if (i >= total4) return;
  float4 v = ((const float4*)x)[i];
  ushort4 o;
  o.x = f2h(v.x); o.y = f2h(v.y); o.z = f2h(v.z); o.w = f2h(v.w);
  ((ushort4*)xh)[i] = o;
}

// W -> packed f16 hi/lo, scaled x256, t-slice-major fragment order:
// slice t (32 k): [hi: 16 ct x 64 lanes x 8 = 8192 u16][lo: 8192 u16]
// frag elem: lane L = q*16+m holds B[k=t*32+q*8+j][n=c*16+m] at (c*64+L)*8+j
__global__ void k_splitW3(const float* __restrict__ W1f, u16* __restrict__ P1,
                          const float* __restrict__ W2f, u16* __restrict__ P2,
                          const float* __restrict__ W3f, u16* __restrict__ P3) {
  int i = blockIdx.x * blockDim.x + threadIdx.x;
  const int s1 = DIN * 256, s2 = s1 + DHID * 256, s3 = s2 + DHID * 256;
  if (i >= s3) return;
  const float* W; u16* P; int li;
  if (i < s1)      { W = W1f; P = P1; li = i; }
  else if (i < s2) { W = W2f; P = P2; li = i - s1; }
  else             { W = W3f; P = P3; li = i - s2; }
  int k = li >> 8, n = li & 255;
  int t = k >> 5, q = (k >> 3) & 3, j = k & 7;
  int c = n >> 4, m = n & 15;
  int f = (c * 64 + q * 16 + m) * 8 + j;
  float w = W[li] * 256.0f;   // scale keeps lo residues f16-normal
  u16 hi = f2h(w);
  u16 lo = f2h(w - h2f(hi));
  P[(size_t)t * 16384 + f] = hi;
  P[(size_t)t * 16384 + 8192 + f] = lo;
}

// Aggregate-first gather: A[node] = dinv^2 * h[node] + sum_e w_e * h[src_e]
// h f16 width 64*CPL; output f16 same width.
template<int CPL>
__global__ __launch_bounds__(256) void k_aggF(const u16* __restrict__ hf,
                                              const float* __restrict__ dinv,
                                              const int* __restrict__ row_ptr,
                                              const int* __restrict__ csr_src,
                                              const float* __restrict__ csr_nrm,
                                              u16* __restrict__ aout, int n) {
  const int W = 64 * CPL;
  int node = blockIdx.x * 4 + (threadIdx.x >> 6);
  if (node >= n) return;
  int lane = threadIdx.x & 63;
  int c = lane * CPL;

  float acc[CPL];
  float di = dinv[node];
  float s2 = di * di;

  auto ldh = [&](int row, float* v) {
    const u16* p = hf + (size_t)row * W + c;
    if constexpr (CPL == 2) {
      unsigned int u = *(const unsigned int*)p;
      v[0] = h2f(u & 0xffffu); v[1] = h2f(u >> 16);
    } else {
      uint2 u = *(const uint2*)p;
      v[0] = h2f(u.x & 0xffffu); v[1] = h2f(u.x >> 16);
      v[2] = h2f(u.y & 0xffffu); v[3] = h2f(u.y >> 16);
    }
  };

  {
    float v[CPL];
    ldh(node, v);
#pragma unroll
    for (int j = 0; j < CPL; ++j) acc[j] = s2 * v[j];
  }

  int p = row_ptr[node], p1 = row_ptr[node + 1];
  for (; p + 4 <= p1; p += 4) {
    int s0 = csr_src[p], s1 = csr_src[p + 1], s2i = csr_src[p + 2], s3 = csr_src[p + 3];
    float w0 = csr_nrm[p], w1 = csr_nrm[p + 1], w2 = csr_nrm[p + 2], w3 = csr_nrm[p + 3];
    float v0[CPL], v1[CPL], v2[CPL], v3[CPL];
    ldh(s0, v0); ldh(s1, v1); ldh(s2i, v2); ldh(s3, v3);
#pragma unroll
    for (int j = 0; j < CPL; ++j) {
      acc[j] = fmaf(w0, v0[j], acc[j]);
      acc[j] = fmaf(w1, v1[j], acc[j]);
      acc[j] = fmaf(w2, v2[j], acc[j]);
      acc[j] = fmaf(w3, v3[j], acc[j]);
    }
  }
  for (; p < p1; ++p) {
    int s = csr_src[p];
    float w = csr_nrm[p];
    float v[CPL];
    ldh(s, v);
#pragma unroll
    for (int j = 0; j < CPL; ++j) acc[j] = fmaf(w, v[j], acc[j]);
  }

  if constexpr (CPL == 2) {
    ushort2 o;
    o.x = f2h(acc[0]); o.y = f2h(acc[1]);
    *(ushort2*)(aout + (size_t)node * W + c) = o;
  } else {
    ushort4 o;
    o.x = f2h(acc[0]); o.y = f2h(acc[1]); o.z = f2h(acc[2]); o.w = f2h(acc[3]);
    *(ushort4*)(aout + (size_t)node * W + c) = o;
  }
}

// C = A[M,K](f16) @ (Bhi+Blo)(f16, x256) / 256 + bias. 2-pass f16 MFMA.
// Block = 64 rows x 256 cols, 4 waves (2 row x 2 col), wave = 32r x 128c.
// B t-slice (32 KB) staged in LDS via global_load_lds, shared by all waves.
// EPI 0: relu + f16 store (all rows). EPI 1: f32 store, rows < NNODES.
template<int K, int EPI>
__global__ __launch_bounds__(256, 4) void k_gemm_mfma(const u16* __restrict__ A,
                                                      const u16* __restrict__ Bpk,
                                                      const float* __restrict__ bias,
                                                      u16* __restrict__ hf16,
                                                      float* __restrict__ outf) {
  __shared__ __align__(16) u16 Bs[16384];   // 32 KB: [hi 8192][lo 8192]
  const int lane = threadIdx.x & 63;
  const int wave = threadIdx.x >> 6;
  const int rw = wave & 1, cw = wave >> 1;
  const int m0 = blockIdx.x * 64 + rw * 32;

  f32x4 acc0[8], acc1[8];
#pragma unroll
  for (int c = 0; c < 8; ++c) {
    acc0[c] = {0.f, 0.f, 0.f, 0.f};
    acc1[c] = {0.f, 0.f, 0.f, 0.f};
  }

  const u16* a0p = A + (size_t)(m0 + (lane & 15)) * K + ((lane >> 4) * 8);
  const u16* a1p = a0p + (size_t)16 * K;

  for (int t = 0; t < K / 32; ++t) {
    __syncthreads();   // previous compute done before Bs overwrite
    {
      const char* gsrc = (const char*)(Bpk + (size_t)t * 16384);
      char* lbase = (char*)Bs;
#pragma unroll
      for (int it = 0; it < 8; ++it) {
        int off = (wave * 8 + it) * 1024 + lane * 16;
        GLDS16(gsrc + off, lbase + off);
      }
    }
    __syncthreads();   // drains vmcnt -> Bs valid

    half8 a0 = *(const half8*)(a0p + t * 32);
    half8 a1 = *(const half8*)(a1p + t * 32);
#pragma unroll
    for (int c = 0; c < 8; ++c) {
      const u16* fb = Bs + ((cw * 8 + c) * 64 + lane) * 8;
      half8 bh = *(const half8*)fb;
      half8 bl = *(const half8*)(fb + 8192);
      acc0[c] = __builtin_amdgcn_mfma_f32_16x16x32_f16(a0, bh, acc0[c], 0, 0, 0);
      acc0[c] = __builtin_amdgcn_mfma_f32_16x16x32_f16(a0, bl, acc0[c], 0, 0, 0);
      acc1[c] = __builtin_amdgcn_mfma_f32_16x16x32_f16(a1, bh, acc1[c], 0, 0, 0);
      acc1[c] = __builtin_amdgcn_mfma_f32_16x16x32_f16(a1, bl, acc1[c], 0, 0, 0);
    }
  }

  const int cbase = lane & 15;
  const int r0 = m0 + ((lane >> 4) * 4);
  const float sc = 1.0f / 256.0f;
#pragma unroll
  for (int c = 0; c < 8; ++c) {
    int col = (cw * 8 + c) * 16 + cbase;
    float bv = bias[col];
#pragma unroll
    for (int r = 0; r < 4; ++r) {
      float v0 = fmaf(acc0[c][r], sc, bv);
      float v1 = fmaf(acc1[c][r], sc, bv);
      if (EPI == 0) {
        v0 = fmaxf(v0, 0.f);
        v1 = fmaxf(v1, 0.f);
        hf16[(size_t)(r0 + r) * 256 + col] = f2h(v0);
        hf16[(size_t)(r0 + 16 + r) * 256 + col] = f2h(v1);
      } else {
        if (r0 + r < NNODES) outf[(size_t)(r0 + r) * 256 + col] = v0;
        if (r0 + 16 + r < NNODES) outf[(size_t)(r0 + 16 + r) * 256 + col] = v1;
      }
    }
  }
}

extern "C" void kernel_launch(void* const* d_in, const int* in_sizes, int n_in,
                              void* d_out, int out_size, void* d_ws, size_t ws_size,
                              hipStream_t stream) {
  const float* x  = (const float*)d_in[0];
  const int*   ei = (const int*)d_in[1];
  const float* W1 = (const float*)d_in[2];
  const float* b1 = (const float*)d_in[3];
  const float* W2 = (const float*)d_in[4];
  const float* b2 = (const float*)d_in[5];
  const float* W3 = (const float*)d_in[6];
  const float* b3 = (const float*)d_in[7];
  float* out = (float*)d_out;
  (void)in_sizes; (void)n_in; (void)out_size; (void)ws_size;

  char* ws = (char*)d_ws;
  size_t off = 0;
  auto alloc = [&](size_t bytes) -> void* {
    void* p = (void*)(ws + off);
    off += (bytes + 255) & ~(size_t)255;
    return p;
  };
  float* dinv    = (float*)alloc((size_t)NNODES * 4);
  int*   deg     = (int*)alloc((size_t)NNODES * 4);
  int*   row_ptr = (int*)alloc((size_t)(NNODES + 1) * 4);
  int*   partials= (int*)alloc((size_t)NSB * 4);
  int*   csr_src = (int*)alloc((size_t)NEDGES * 4);
  float* csr_nrm = (float*)alloc((size_t)NEDGES * 4);
  u16*   xh      = (u16*)alloc((size_t)NNODES * DIN * 2);    // x as f16
  u16*   hbuf    = (u16*)alloc((size_t)MPAD * 256 * 2);      // h f16 (gather src)
  u16*   A1      = (u16*)alloc((size_t)MPAD * DIN * 2);      // agg(x) f16
  u16*   A2      = (u16*)alloc((size_t)MPAD * 256 * 2);      // agg(h) f16
  u16*   W1pk    = (u16*)alloc((size_t)(DIN / 32) * 16384 * 2);
  u16*   W2pk    = (u16*)alloc((size_t)(DHID / 32) * 16384 * 2);
  u16*   W3pk    = (u16*)alloc((size_t)(DHID / 32) * 16384 * 2);

  const int* e_src = ei;
  const int* e_dst = ei + NEDGES;

  const int tb = 256;
  k_zero_i32<<<(NNODES + tb - 1) / tb, tb, 0, stream>>>(deg, NNODES);
  k_hist<<<(NEDGES + tb - 1) / tb, tb, 0, stream>>>(e_dst, deg, NEDGES);
  k_blocksum<<<NSB, 256, 0, stream>>>(deg, partials);
  k_scan2<<<NSB, 256, 0, stream>>>(deg, partials, row_ptr, dinv);
  k_fill<<<(NEDGES + tb - 1) / tb, tb, 0, stream>>>(e_src, e_dst, dinv, row_ptr, deg,
                                                    csr_src, csr_nrm, NEDGES);

  int x4 = NNODES * DIN / 4;
  k_x2f16<<<(x4 + tb - 1) / tb, tb, 0, stream>>>(x, xh, x4);
  int wtot = (DIN + DHID + DHID) * 256;
  k_splitW3<<<(wtot + tb - 1) / tb, tb, 0, stream>>>(W1, W1pk, W2, W2pk, W3, W3pk);

  const int gblocks = MPAD / 64;           // 782
  const int ablocks = (NNODES + 3) / 4;

  // layer 1
  k_aggF<2><<<ablocks, 256, 0, stream>>>(xh, dinv, row_ptr, csr_src, csr_nrm,
                                         A1, NNODES);
  k_gemm_mfma<DIN, 0><<<gblocks, 256, 0, stream>>>(A1, W1pk, b1, hbuf, nullptr);
  // layer 2
  k_aggF<4><<<ablocks, 256, 0, stream>>>(hbuf, dinv, row_ptr, csr_src, csr_nrm,
                                         A2, NNODES);
  k_gemm_mfma<DHID, 0><<<gblocks, 256, 0, stream>>>(A2, W2pk, b2, hbuf, nullptr);
  // layer 3
  k_aggF<4><<<ablocks, 256, 0, stream>>>(hbuf, dinv, row_ptr, csr_src, csr_nrm,
                                         A2, NNODES);
  k_gemm_mfma<DHID, 1><<<gblocks, 256, 0, stream>>>(A2, W3pk, b3, nullptr, out);
}